// Round 8
// baseline (1077.198 us; speedup 1.0000x reference)
//
#include <hip/hip_runtime.h>
#include <hip/hip_bf16.h>

// Problem constants (B=16, N=S=2048, D=256, fp32 in/out).
#define BB 16
#define NN 2048
#define SS 2048
#define DD 256
#define EE (BB * NN * DD)  // 8388608 elements per tensor
#define QP 264             // padded LDS pitch (f16) for Q strip rows

typedef _Float16 f16x8 __attribute__((ext_vector_type(8)));
typedef _Float16 f16x4 __attribute__((ext_vector_type(4)));
typedef float floatx4 __attribute__((ext_vector_type(4)));

__device__ __forceinline__ void async16(const _Float16* g, _Float16* l) {
    __builtin_amdgcn_global_load_lds((__attribute__((address_space(1))) void*)g,
                                     (__attribute__((address_space(3))) void*)l, 16, 0, 0);
}

__device__ __forceinline__ void nt_store4(float* p, float x, float y, float z, float w) {
    floatx4 v = {x, y, z, w};
    __builtin_nontemporal_store(v, (floatx4*)p);
}

// ===========================================================================
// MEGA PATH (requires ws_size >= EE fp16 bytes for the Kh stash)
// ===========================================================================

// K -> fp16 (hi only). 2-term asymmetric split: q = qh+ql exact, k ~ kh.
__global__ __launch_bounds__(256) void k_convert_k(const float* __restrict__ K,
                                                   _Float16* __restrict__ kh) {
    size_t idx = ((size_t)blockIdx.x * 256 + threadIdx.x) * 4;  // over EE
    float4 v = *(const float4*)(K + idx);
    f16x4 h;
    h.x = (_Float16)v.x; h.y = (_Float16)v.y; h.z = (_Float16)v.z; h.w = (_Float16)v.w;
    *(f16x4*)(kh + idx) = h;
}

// One block = 16 query rows x full S. Phases:
//  0: load Q strip fp32, split to fp16 hi/lo in LDS (padded pitch)
//  1: K=256 MFMA loop, B-frags streamed global->VGPR (no barriers, no LDS for K)
//  2: per-row sparsemax tau (group shuffles + small cross-wave LDS reductions)
//  3: gates = max(score-tau,0) in-place in acc; nt-store to G and A
//  4: sparse PV via ballot into Vacc[16] (float4/lane); cross-wave LDS reduce; nt V
__global__ __launch_bounds__(256, 1) void k_mega(const float* __restrict__ Qin,
                                                 const _Float16* __restrict__ Kh,
                                                 const float* __restrict__ Val,
                                                 float* __restrict__ G,
                                                 float* __restrict__ A,
                                                 float* __restrict__ Vout) {
    __shared__ float smem[16384 + 192];  // 64KB Vred (overlays Q) + 3x64 red bufs
    _Float16* Qh_lds = (_Float16*)smem;             // 16 x QP f16
    _Float16* Ql_lds = (_Float16*)smem + 16 * QP;   // 16 x QP f16 (total 16.9KB)
    float* Vred = smem;                              // 4x16x256 f32 = 64KB (phase 4)
    float* Mred = smem + 16384;                      // 64
    float* S0   = smem + 16384 + 64;                 // 64
    float* S1   = smem + 16384 + 128;                // 64

    const int blk  = blockIdx.x;
    const int b    = blk >> 7;            // batch
    const int n0   = (blk & 127) << 4;    // strip start row
    const int t    = threadIdx.x;
    const int wave = t >> 6;
    const int lane = t & 63;
    const int grp  = lane >> 4;           // 0..3
    const int sl   = lane & 15;

    // ---- phase 0: Q strip -> LDS fp16 hi/lo (padded)
    {
        const int row = t >> 4;           // 0..15
        const int dc  = (t & 15) << 4;    // 0..240
        const float* qs = Qin + ((size_t)b * NN + n0 + row) * DD + dc;
#pragma unroll
        for (int j = 0; j < 4; ++j) {
            float4 v = *(const float4*)(qs + j * 4);
            f16x4 h, l;
            h.x = (_Float16)v.x; h.y = (_Float16)v.y; h.z = (_Float16)v.z; h.w = (_Float16)v.w;
            l.x = (_Float16)(v.x - (float)h.x);
            l.y = (_Float16)(v.y - (float)h.y);
            l.z = (_Float16)(v.z - (float)h.z);
            l.w = (_Float16)(v.w - (float)h.w);
            *(f16x4*)&Qh_lds[row * QP + dc + j * 4] = h;
            *(f16x4*)&Ql_lds[row * QP + dc + j * 4] = l;
        }
    }
    __syncthreads();

    // ---- phase 1: scores. wave owns cols [wave*512, wave*512+512) as 32 tiles.
    const _Float16* kb = Kh + ((size_t)b * SS + wave * 512) * DD;
    floatx4 acc[32];
#pragma unroll
    for (int tt = 0; tt < 32; ++tt) acc[tt] = (floatx4){0.f, 0.f, 0.f, 0.f};

    const int fq = sl * QP + grp * 8;   // A-frag: m=sl, k=grp*8+j
    for (int d0 = 0; d0 < DD; d0 += 32) {
        f16x8 qh = *(const f16x8*)&Qh_lds[fq + d0];
        f16x8 ql = *(const f16x8*)&Ql_lds[fq + d0];
#pragma unroll
        for (int tt = 0; tt < 32; ++tt) {
            f16x8 kf = *(const f16x8*)(kb + (size_t)(tt * 16 + sl) * DD + d0 + grp * 8);
            acc[tt] = __builtin_amdgcn_mfma_f32_16x16x32_f16(qh, kf, acc[tt], 0, 0, 0);
            acc[tt] = __builtin_amdgcn_mfma_f32_16x16x32_f16(ql, kf, acc[tt], 0, 0, 0);
        }
    }
    // C-layout: lane holds rows grp*4+rr (rr=reg), col = tile*16 + sl.

    // ---- phase 2: per-row tau. All 16 lanes of a group share the same 4 rows.
    float lo[4], hi[4];
    {
        float mx[4];
#pragma unroll
        for (int rr = 0; rr < 4; ++rr) {
            float m = acc[0][rr];
#pragma unroll
            for (int tt = 1; tt < 32; ++tt) m = fmaxf(m, acc[tt][rr]);
            mx[rr] = m;
        }
#pragma unroll
        for (int off = 1; off < 16; off <<= 1)
#pragma unroll
            for (int rr = 0; rr < 4; ++rr)
                mx[rr] = fmaxf(mx[rr], __shfl_xor(mx[rr], off, 64));
        if (sl == 0)
#pragma unroll
            for (int rr = 0; rr < 4; ++rr) Mred[wave * 16 + grp * 4 + rr] = mx[rr];
        __syncthreads();
#pragma unroll
        for (int rr = 0; rr < 4; ++rr) {
            int o = grp * 4 + rr;
            float m = fmaxf(fmaxf(Mred[o], Mred[16 + o]), fmaxf(Mred[32 + o], Mred[48 + o]));
            lo[rr] = m - 1.0f; hi[rr] = m;
        }
        __syncthreads();
    }
    // bisection x10 (alternating buffers -> 1 barrier per iter)
    for (int it = 0; it < 10; ++it) {
        float* Sw = (it & 1) ? S1 : S0;
        float mid[4], p[4];
#pragma unroll
        for (int rr = 0; rr < 4; ++rr) { mid[rr] = 0.5f * (lo[rr] + hi[rr]); p[rr] = 0.f; }
#pragma unroll
        for (int tt = 0; tt < 32; ++tt)
#pragma unroll
            for (int rr = 0; rr < 4; ++rr) p[rr] += fmaxf(acc[tt][rr] - mid[rr], 0.f);
#pragma unroll
        for (int off = 1; off < 16; off <<= 1)
#pragma unroll
            for (int rr = 0; rr < 4; ++rr) p[rr] += __shfl_xor(p[rr], off, 64);
        if (sl == 0)
#pragma unroll
            for (int rr = 0; rr < 4; ++rr) Sw[wave * 16 + grp * 4 + rr] = p[rr];
        __syncthreads();
#pragma unroll
        for (int rr = 0; rr < 4; ++rr) {
            int o = grp * 4 + rr;
            float P = Sw[o] + Sw[16 + o] + Sw[32 + o] + Sw[48 + o];
            if (P >= 1.0f) lo[rr] = mid[rr]; else hi[rr] = mid[rr];
        }
    }
    // Michelot x4 (exact fixpoint): sum in S0, count in S1, 2 barriers per iter
    float tau[4];
#pragma unroll
    for (int rr = 0; rr < 4; ++rr) tau[rr] = lo[rr];
    for (int it = 0; it < 4; ++it) {
        float sm[4], ct[4];
#pragma unroll
        for (int rr = 0; rr < 4; ++rr) { sm[rr] = 0.f; ct[rr] = 0.f; }
#pragma unroll
        for (int tt = 0; tt < 32; ++tt)
#pragma unroll
            for (int rr = 0; rr < 4; ++rr) {
                float z = acc[tt][rr];
                if (z > tau[rr]) { sm[rr] += z; ct[rr] += 1.0f; }
            }
#pragma unroll
        for (int off = 1; off < 16; off <<= 1)
#pragma unroll
            for (int rr = 0; rr < 4; ++rr) {
                sm[rr] += __shfl_xor(sm[rr], off, 64);
                ct[rr] += __shfl_xor(ct[rr], off, 64);
            }
        __syncthreads();  // ensure prior-iter reads done before overwrite
        if (sl == 0)
#pragma unroll
            for (int rr = 0; rr < 4; ++rr) {
                S0[wave * 16 + grp * 4 + rr] = sm[rr];
                S1[wave * 16 + grp * 4 + rr] = ct[rr];
            }
        __syncthreads();
#pragma unroll
        for (int rr = 0; rr < 4; ++rr) {
            int o = grp * 4 + rr;
            float S = S0[o] + S0[16 + o] + S0[32 + o] + S0[48 + o];
            float C = S1[o] + S1[16 + o] + S1[32 + o] + S1[48 + o];
            tau[rr] = (S - 1.0f) / C;
        }
    }

    // ---- phase 3: gates in-place + nt stores to G and A
#pragma unroll
    for (int tt = 0; tt < 32; ++tt) {
#pragma unroll
        for (int rr = 0; rr < 4; ++rr) {
            float gg = fmaxf(acc[tt][rr] - tau[rr], 0.f);
            acc[tt][rr] = gg;
            size_t addr = ((size_t)b * NN + n0 + grp * 4 + rr) * SS + wave * 512 + tt * 16 + sl;
            __builtin_nontemporal_store(gg, G + addr);
            __builtin_nontemporal_store(gg, A + addr);
        }
    }

    // ---- phase 4: sparse PV. Vacc[row] float4 per lane (d = lane*4..+3).
    floatx4 vac[16];
#pragma unroll
    for (int r = 0; r < 16; ++r) vac[r] = (floatx4){0.f, 0.f, 0.f, 0.f};
    const float* vb = Val + (size_t)b * SS * DD;
#pragma unroll
    for (int tt = 0; tt < 32; ++tt) {
#pragma unroll
        for (int rr = 0; rr < 4; ++rr) {
            float gg = acc[tt][rr];
            unsigned long long mask = __ballot(gg > 0.f);
            while (mask) {
                int src = __builtin_ctzll(mask);
                mask &= mask - 1;
                float aa = __shfl(gg, src, 64);
                int sg = src >> 4;
                int s = wave * 512 + tt * 16 + (src & 15);
                floatx4 vv = *(const floatx4*)(vb + (size_t)s * DD + lane * 4);
                switch (sg) {
                    case 0: vac[0 + rr] += vv * aa; break;
                    case 1: vac[4 + rr] += vv * aa; break;
                    case 2: vac[8 + rr] += vv * aa; break;
                    default: vac[12 + rr] += vv * aa; break;
                }
            }
        }
    }
    __syncthreads();  // Q/red LDS dead everywhere; Vred writes begin
#pragma unroll
    for (int r = 0; r < 16; ++r)
        *(floatx4*)&Vred[wave * 4096 + r * 256 + lane * 4] = vac[r];
    __syncthreads();
    {
        const int row = t >> 4;
        const int c0 = (t & 15) << 4;
        float* vout = Vout + ((size_t)b * NN + n0 + row) * DD + c0;
#pragma unroll
        for (int j = 0; j < 4; ++j) {
            floatx4 a0 = *(floatx4*)&Vred[row * 256 + c0 + j * 4];
            floatx4 a1 = *(floatx4*)&Vred[4096 + row * 256 + c0 + j * 4];
            floatx4 a2 = *(floatx4*)&Vred[8192 + row * 256 + c0 + j * 4];
            floatx4 a3 = *(floatx4*)&Vred[12288 + row * 256 + c0 + j * 4];
            floatx4 sv = a0 + a1 + a2 + a3;
            __builtin_nontemporal_store(sv, (floatx4*)(vout + j * 4));
        }
    }
}

// ===========================================================================
// FALLBACK PATH — R7 verbatim (735 us, passed) — used if ws too small
// ===========================================================================
__global__ __launch_bounds__(256) void k_convert(const float* __restrict__ Q,
                                                 const float* __restrict__ K,
                                                 _Float16* __restrict__ stash) {
    size_t idx = ((size_t)blockIdx.x * 256 + threadIdx.x) * 4;
    if (idx < (size_t)EE) {
        float4 v = *(const float4*)(Q + idx);
        f16x4 h, l;
        h.x = (_Float16)v.x; h.y = (_Float16)v.y; h.z = (_Float16)v.z; h.w = (_Float16)v.w;
        l.x = (_Float16)(v.x - (float)h.x);
        l.y = (_Float16)(v.y - (float)h.y);
        l.z = (_Float16)(v.z - (float)h.z);
        l.w = (_Float16)(v.w - (float)h.w);
        *(f16x4*)(stash + idx) = h;
        *(f16x4*)(stash + (size_t)EE + idx) = l;
    } else {
        size_t off = idx - (size_t)EE;
        float4 v = *(const float4*)(K + off);
        f16x4 h;
        h.x = (_Float16)v.x; h.y = (_Float16)v.y; h.z = (_Float16)v.z; h.w = (_Float16)v.w;
        *(f16x4*)(stash + 2 * (size_t)EE + off) = h;
    }
}

__global__ __launch_bounds__(256) void k_scores_mfma(const _Float16* __restrict__ stash,
                                                     float* __restrict__ out) {
    __shared__ _Float16 Qh[128 * 32];
    __shared__ _Float16 Ql[128 * 32];
    __shared__ _Float16 Kh[128 * 32];

    const _Float16* Qhi = stash;
    const _Float16* Qlo = stash + (size_t)EE;
    const _Float16* Khi = stash + 2 * (size_t)EE;

    const int b  = blockIdx.z;
    const int n0 = blockIdx.y * 128;
    const int s0 = blockIdx.x * 128;
    const int t    = threadIdx.x;
    const int wave = t >> 6;
    const int lane = t & 63;
    const int srow = (wave << 4) + (lane >> 2);
    const int sd   = (lane & 3) << 3;
    const int lds0 = srow * 32 + sd;
    const size_t qg = (size_t)b * NN * DD + (size_t)(n0 + srow) * DD + sd;
    const size_t kg = (size_t)b * SS * DD + (size_t)(s0 + srow) * DD + sd;
    const int wy = wave >> 1, wx = wave & 1;
    const int frag = (lane & 15) * 32 + (lane >> 4) * 8;

    floatx4 acc[4][4] = {};
    for (int d0 = 0; d0 < DD; d0 += 32) {
        __syncthreads();
        async16(Qhi + qg + d0,            &Qh[lds0]);
        async16(Qhi + qg + d0 + 64 * DD,  &Qh[lds0 + 2048]);
        async16(Qlo + qg + d0,            &Ql[lds0]);
        async16(Qlo + qg + d0 + 64 * DD,  &Ql[lds0 + 2048]);
        async16(Khi + kg + d0,            &Kh[lds0]);
        async16(Khi + kg + d0 + 64 * DD,  &Kh[lds0 + 2048]);
        __syncthreads();
        f16x8 qh[4], ql[4], kh[4];
#pragma unroll
        for (int i = 0; i < 4; ++i) {
            qh[i] = *(const f16x8*)&Qh[(wy * 64 + i * 16) * 32 + frag];
            ql[i] = *(const f16x8*)&Ql[(wy * 64 + i * 16) * 32 + frag];
            kh[i] = *(const f16x8*)&Kh[(wx * 64 + i * 16) * 32 + frag];
        }
#pragma unroll
        for (int i = 0; i < 4; ++i)
#pragma unroll
            for (int j = 0; j < 4; ++j) {
                acc[i][j] = __builtin_amdgcn_mfma_f32_16x16x32_f16(qh[i], kh[j], acc[i][j], 0, 0, 0);
                acc[i][j] = __builtin_amdgcn_mfma_f32_16x16x32_f16(ql[i], kh[j], acc[i][j], 0, 0, 0);
            }
    }
    float* ob = out + (size_t)b * NN * SS;
    const int r0 = n0 + wy * 64 + (lane >> 4) * 4;
    const int c0 = s0 + wx * 64 + (lane & 15);
#pragma unroll
    for (int i = 0; i < 4; ++i)
#pragma unroll
        for (int j = 0; j < 4; ++j)
#pragma unroll
            for (int r = 0; r < 4; ++r)
                ob[(size_t)(r0 + i * 16 + r) * SS + c0 + j * 16] = acc[i][j][r];
}

__global__ __launch_bounds__(256) void k_sparsemax_pv(float* __restrict__ G,
                                                      float* __restrict__ A,
                                                      const float* __restrict__ Val,
                                                      float* __restrict__ Vout) {
    const int t = threadIdx.x;
    const int lane = t & 63;
    const size_t rblk = (size_t)(gridDim.x - 1 - blockIdx.x);
    const size_t row = rblk * 4 + (t >> 6);
    const int b = (int)(row >> 11);
    float* z = G + row * SS;
    float* arow = A + row * SS;
    const float* vb = Val + (size_t)b * SS * DD;

    float v[32];
#pragma unroll
    for (int c = 0; c < 8; ++c) {
        float4 zz = *(const float4*)(z + c * 256 + (lane << 2));
        v[c * 4 + 0] = zz.x; v[c * 4 + 1] = zz.y; v[c * 4 + 2] = zz.z; v[c * 4 + 3] = zz.w;
    }
    float m = v[0];
#pragma unroll
    for (int j = 1; j < 32; ++j) m = fmaxf(m, v[j]);
#pragma unroll
    for (int off = 32; off > 0; off >>= 1) m = fmaxf(m, __shfl_xor(m, off, 64));
    float lo = m - 1.0f, hi = m;
    for (int it = 0; it < 10; ++it) {
        float mid = 0.5f * (lo + hi);
        float p = 0.f;
#pragma unroll
        for (int j = 0; j < 32; ++j) p += fmaxf(v[j] - mid, 0.f);
#pragma unroll
        for (int off = 32; off > 0; off >>= 1) p += __shfl_xor(p, off, 64);
        if (p >= 1.0f) lo = mid; else hi = mid;
    }
    float tau = lo;
#pragma unroll
    for (int it = 0; it < 4; ++it) {
        float cnt = 0.f, s = 0.f;
#pragma unroll
        for (int j = 0; j < 32; ++j) {
            if (v[j] > tau) { cnt += 1.0f; s += v[j]; }
        }
#pragma unroll
        for (int off = 32; off > 0; off >>= 1) {
            cnt += __shfl_xor(cnt, off, 64);
            s   += __shfl_xor(s, off, 64);
        }
        tau = (s - 1.0f) / cnt;
    }
    float g[32];
#pragma unroll
    for (int c = 0; c < 8; ++c) {
#pragma unroll
        for (int q = 0; q < 4; ++q) g[c * 4 + q] = fmaxf(v[c * 4 + q] - tau, 0.f);
        nt_store4(z + c * 256 + (lane << 2),    g[c * 4], g[c * 4 + 1], g[c * 4 + 2], g[c * 4 + 3]);
        nt_store4(arow + c * 256 + (lane << 2), g[c * 4], g[c * 4 + 1], g[c * 4 + 2], g[c * 4 + 3]);
    }
    float4 acc = make_float4(0.f, 0.f, 0.f, 0.f);
#pragma unroll
    for (int c = 0; c < 8; ++c) {
#pragma unroll
        for (int q = 0; q < 4; ++q) {
            float a = g[c * 4 + q];
            unsigned long long mask = __ballot(a != 0.0f);
            while (mask) {
                int src = __builtin_ctzll(mask);
                mask &= mask - 1;
                float aa = __shfl(a, src, 64);
                int s = c * 256 + src * 4 + q;
                float4 vv = *(const float4*)(vb + (size_t)s * DD + lane * 4);
                acc.x += aa * vv.x;
                acc.y += aa * vv.y;
                acc.z += aa * vv.z;
                acc.w += aa * vv.w;
            }
        }
    }
    nt_store4(Vout + row * DD + lane * 4, acc.x, acc.y, acc.z, acc.w);
}

extern "C" void kernel_launch(void* const* d_in, const int* in_sizes, int n_in,
                              void* d_out, int out_size, void* d_ws, size_t ws_size,
                              hipStream_t stream) {
    const float* Q = (const float*)d_in[0];
    const float* K = (const float*)d_in[1];
    const float* V = (const float*)d_in[2];

    float* out  = (float*)d_out;
    float* Vout = out;                                   // [B,N,D]
    float* Aout = out + (size_t)BB * NN * DD;            // [B,N,S]
    float* Gout = Aout + (size_t)BB * NN * SS;           // [B,N,S]

    if (ws_size >= (size_t)EE * sizeof(_Float16)) {
        // MEGA PATH: Kh stash in workspace; one fused kernel for everything else.
        _Float16* kh = (_Float16*)d_ws;
        hipLaunchKernelGGL(k_convert_k, dim3(EE / 4 / 256), dim3(256), 0, stream, K, kh);
        hipLaunchKernelGGL(k_mega, dim3(BB * (NN / 16)), dim3(256), 0, stream,
                           Q, kh, V, Gout, Aout, Vout);
    } else {
        // FALLBACK: proven R7 3-kernel pipeline (stash in Aout region).
        _Float16* stash = (_Float16*)Aout;
        hipLaunchKernelGGL(k_convert, dim3((2 * EE / 4) / 256), dim3(256), 0, stream, Q, K, stash);
        dim3 g1(SS / 128, NN / 128, BB);
        hipLaunchKernelGGL(k_scores_mfma, g1, dim3(256), 0, stream, stash, Gout);
        hipLaunchKernelGGL(k_sparsemax_pv, dim3((BB * NN) / 4), dim3(256), 0, stream,
                           Gout, Aout, V, Vout);
    }
}

// Round 9
// 993.911 us; speedup vs baseline: 1.0838x; 1.0838x over previous
//
#include <hip/hip_runtime.h>
#include <hip/hip_bf16.h>

// Problem constants (B=16, N=S=2048, D=256, fp32 in/out).
#define BB 16
#define NN 2048
#define SS 2048
#define DD 256
#define EE (BB * NN * DD)  // 8388608 elements per tensor
#define QP 264             // padded LDS pitch (f16) for Q strip rows
#define LCAP 32            // list capacity per row per wave (support ~1-3 observed)

typedef _Float16 f16x8 __attribute__((ext_vector_type(8)));
typedef _Float16 f16x4 __attribute__((ext_vector_type(4)));
typedef float floatx4 __attribute__((ext_vector_type(4)));

__device__ __forceinline__ void async16(const _Float16* g, _Float16* l) {
    __builtin_amdgcn_global_load_lds((__attribute__((address_space(1))) void*)g,
                                     (__attribute__((address_space(3))) void*)l, 16, 0, 0);
}

__device__ __forceinline__ void nt_store4(float* p, float x, float y, float z, float w) {
    floatx4 v = {x, y, z, w};
    __builtin_nontemporal_store(v, (floatx4*)p);
}

// ===========================================================================
// MEGA PATH (requires ws_size >= EE fp16 bytes for the Kh stash)
// ===========================================================================

__global__ __launch_bounds__(256) void k_convert_k(const float* __restrict__ K,
                                                   _Float16* __restrict__ kh) {
    size_t idx = ((size_t)blockIdx.x * 256 + threadIdx.x) * 4;  // over EE
    float4 v = *(const float4*)(K + idx);
    f16x4 h;
    h.x = (_Float16)v.x; h.y = (_Float16)v.y; h.z = (_Float16)v.z; h.w = (_Float16)v.w;
    *(f16x4*)(kh + idx) = h;
}

// One block = 16 query rows x full S.
//  0: Q strip fp32 -> fp16 hi/lo in LDS (padded pitch)
//  1: scores: K=256 MFMA loop, B-frags streamed global->VGPR (acc[32]/wave)
//  2: per-row tau (group shuffles + small cross-wave LDS reductions)
//  3: gates: nt-store to G,A + ballot-prefix append of nonzeros to LDS lists
//     (lists overlay the dead Q buffers; no atomics, no vac registers)
//  4: per-row gather: 16 threads/row read the tiny list, gather V, nt-store
__global__ __launch_bounds__(256, 2) void k_mega(const float* __restrict__ Qin,
                                                 const _Float16* __restrict__ Kh,
                                                 const float* __restrict__ Val,
                                                 float* __restrict__ G,
                                                 float* __restrict__ A,
                                                 float* __restrict__ Vout) {
    __shared__ __align__(16) float fsmem[4480];  // 17.92 KB total
    _Float16* Qh_lds = (_Float16*)fsmem;              // 16 x QP f16
    _Float16* Ql_lds = (_Float16*)fsmem + 16 * QP;    // 16 x QP f16 (16.9 KB)
    int*   cols_l = (int*)fsmem;                      // [16][4][LCAP] 8KB (overlay)
    float* vals_l = fsmem + 2048;                     // [16][4][LCAP] 8KB (overlay)
    float* Mred = fsmem + 4224;                       // [64]
    float* S0   = fsmem + 4288;                       // [64]
    float* S1   = fsmem + 4352;                       // [64]
    int*   cnts = (int*)(fsmem + 4416);               // [16][4]

    const int blk  = blockIdx.x;
    const int b    = blk >> 7;            // batch
    const int n0   = (blk & 127) << 4;    // strip start row
    const int t    = threadIdx.x;
    const int wave = t >> 6;
    const int lane = t & 63;
    const int grp  = lane >> 4;           // 0..3
    const int sl   = lane & 15;

    // ---- phase 0: Q strip -> LDS fp16 hi/lo (padded)
    {
        const int row = t >> 4;           // 0..15
        const int dc  = (t & 15) << 4;    // 0..240
        const float* qs = Qin + ((size_t)b * NN + n0 + row) * DD + dc;
#pragma unroll
        for (int j = 0; j < 4; ++j) {
            float4 v = *(const float4*)(qs + j * 4);
            f16x4 h, l;
            h.x = (_Float16)v.x; h.y = (_Float16)v.y; h.z = (_Float16)v.z; h.w = (_Float16)v.w;
            l.x = (_Float16)(v.x - (float)h.x);
            l.y = (_Float16)(v.y - (float)h.y);
            l.z = (_Float16)(v.z - (float)h.z);
            l.w = (_Float16)(v.w - (float)h.w);
            *(f16x4*)&Qh_lds[row * QP + dc + j * 4] = h;
            *(f16x4*)&Ql_lds[row * QP + dc + j * 4] = l;
        }
    }
    __syncthreads();

    // ---- phase 1: scores. wave owns cols [wave*512, wave*512+512) as 32 tiles.
    const _Float16* kb = Kh + ((size_t)b * SS + wave * 512) * DD;
    floatx4 acc[32];
#pragma unroll
    for (int tt = 0; tt < 32; ++tt) acc[tt] = (floatx4){0.f, 0.f, 0.f, 0.f};

    const int fq = sl * QP + grp * 8;   // A-frag: m=sl, k=grp*8+j
    for (int d0 = 0; d0 < DD; d0 += 32) {
        f16x8 qh = *(const f16x8*)&Qh_lds[fq + d0];
        f16x8 ql = *(const f16x8*)&Ql_lds[fq + d0];
#pragma unroll
        for (int tt = 0; tt < 32; ++tt) {
            f16x8 kf = *(const f16x8*)(kb + (size_t)(tt * 16 + sl) * DD + d0 + grp * 8);
            acc[tt] = __builtin_amdgcn_mfma_f32_16x16x32_f16(qh, kf, acc[tt], 0, 0, 0);
            acc[tt] = __builtin_amdgcn_mfma_f32_16x16x32_f16(ql, kf, acc[tt], 0, 0, 0);
        }
    }
    // C-layout: lane holds rows grp*4+rr (rr=reg), col = tile*16 + sl.

    // ---- phase 2: per-row tau.
    float lo[4], hi[4];
    {
        float mx[4];
#pragma unroll
        for (int rr = 0; rr < 4; ++rr) {
            float m = acc[0][rr];
#pragma unroll
            for (int tt = 1; tt < 32; ++tt) m = fmaxf(m, acc[tt][rr]);
            mx[rr] = m;
        }
#pragma unroll
        for (int off = 1; off < 16; off <<= 1)
#pragma unroll
            for (int rr = 0; rr < 4; ++rr)
                mx[rr] = fmaxf(mx[rr], __shfl_xor(mx[rr], off, 64));
        if (sl == 0)
#pragma unroll
            for (int rr = 0; rr < 4; ++rr) Mred[wave * 16 + grp * 4 + rr] = mx[rr];
        __syncthreads();
#pragma unroll
        for (int rr = 0; rr < 4; ++rr) {
            int o = grp * 4 + rr;
            float m = fmaxf(fmaxf(Mred[o], Mred[16 + o]), fmaxf(Mred[32 + o], Mred[48 + o]));
            lo[rr] = m - 1.0f; hi[rr] = m;
        }
        __syncthreads();
    }
    // bisection x10 (alternating buffers -> 1 barrier per iter)
    for (int it = 0; it < 10; ++it) {
        float* Sw = (it & 1) ? S1 : S0;
        float mid[4], p[4];
#pragma unroll
        for (int rr = 0; rr < 4; ++rr) { mid[rr] = 0.5f * (lo[rr] + hi[rr]); p[rr] = 0.f; }
#pragma unroll
        for (int tt = 0; tt < 32; ++tt)
#pragma unroll
            for (int rr = 0; rr < 4; ++rr) p[rr] += fmaxf(acc[tt][rr] - mid[rr], 0.f);
#pragma unroll
        for (int off = 1; off < 16; off <<= 1)
#pragma unroll
            for (int rr = 0; rr < 4; ++rr) p[rr] += __shfl_xor(p[rr], off, 64);
        if (sl == 0)
#pragma unroll
            for (int rr = 0; rr < 4; ++rr) Sw[wave * 16 + grp * 4 + rr] = p[rr];
        __syncthreads();
#pragma unroll
        for (int rr = 0; rr < 4; ++rr) {
            int o = grp * 4 + rr;
            float P = Sw[o] + Sw[16 + o] + Sw[32 + o] + Sw[48 + o];
            if (P >= 1.0f) lo[rr] = mid[rr]; else hi[rr] = mid[rr];
        }
    }
    // Michelot x4 (exact fixpoint)
    float tau[4];
#pragma unroll
    for (int rr = 0; rr < 4; ++rr) tau[rr] = lo[rr];
    for (int it = 0; it < 4; ++it) {
        float sm[4], ct[4];
#pragma unroll
        for (int rr = 0; rr < 4; ++rr) { sm[rr] = 0.f; ct[rr] = 0.f; }
#pragma unroll
        for (int tt = 0; tt < 32; ++tt)
#pragma unroll
            for (int rr = 0; rr < 4; ++rr) {
                float z = acc[tt][rr];
                if (z > tau[rr]) { sm[rr] += z; ct[rr] += 1.0f; }
            }
#pragma unroll
        for (int off = 1; off < 16; off <<= 1)
#pragma unroll
            for (int rr = 0; rr < 4; ++rr) {
                sm[rr] += __shfl_xor(sm[rr], off, 64);
                ct[rr] += __shfl_xor(ct[rr], off, 64);
            }
        __syncthreads();
        if (sl == 0)
#pragma unroll
            for (int rr = 0; rr < 4; ++rr) {
                S0[wave * 16 + grp * 4 + rr] = sm[rr];
                S1[wave * 16 + grp * 4 + rr] = ct[rr];
            }
        __syncthreads();
#pragma unroll
        for (int rr = 0; rr < 4; ++rr) {
            int o = grp * 4 + rr;
            float S = S0[o] + S0[16 + o] + S0[32 + o] + S0[48 + o];
            float C = S1[o] + S1[16 + o] + S1[32 + o] + S1[48 + o];
            tau[rr] = (S - 1.0f) / C;
        }
    }
    __syncthreads();  // Q LDS fully dead (phase 1 done everywhere); lists may now overlay

    // ---- phase 3: gates -> nt stores to G,A + ballot-prefix list append
    int cnt[4] = {0, 0, 0, 0};
#pragma unroll
    for (int tt = 0; tt < 32; ++tt) {
#pragma unroll
        for (int rr = 0; rr < 4; ++rr) {
            float gg = fmaxf(acc[tt][rr] - tau[rr], 0.f);
            const int row = grp * 4 + rr;
            const int col = wave * 512 + tt * 16 + sl;
            size_t addr = ((size_t)b * NN + n0 + row) * SS + col;
            __builtin_nontemporal_store(gg, G + addr);
            __builtin_nontemporal_store(gg, A + addr);
            unsigned long long m = __ballot(gg > 0.f);
            unsigned mg = (unsigned)(m >> (grp * 16)) & 0xFFFFu;
            if (gg > 0.f) {
                int idx = cnt[rr] + __popc(mg & ((1u << sl) - 1u));
                if (idx < LCAP) {
                    cols_l[(row * 4 + wave) * LCAP + idx] = col;
                    vals_l[(row * 4 + wave) * LCAP + idx] = gg;
                }
            }
            cnt[rr] += __popc(mg);
        }
    }
    if (sl == 0)
#pragma unroll
        for (int rr = 0; rr < 4; ++rr) {
            int c = cnt[rr]; if (c > LCAP) c = LCAP;
            cnts[(grp * 4 + rr) * 4 + wave] = c;
        }
    __syncthreads();

    // ---- phase 4: per-row V gather. 16 threads per row, 16 d-elems each.
    {
        const int row = t >> 4;           // 0..15
        const int dc  = (t & 15) << 4;    // 0..240
        const float* vb = Val + (size_t)b * SS * DD;
        floatx4 a0 = {0.f, 0.f, 0.f, 0.f}, a1 = a0, a2 = a0, a3 = a0;
#pragma unroll
        for (int w = 0; w < 4; ++w) {
            const int c = cnts[row * 4 + w];
            for (int i = 0; i < c; ++i) {
                const int col = cols_l[(row * 4 + w) * LCAP + i];
                const float aa = vals_l[(row * 4 + w) * LCAP + i];
                const float* vp = vb + (size_t)col * DD + dc;
                a0 += *(const floatx4*)(vp + 0) * aa;
                a1 += *(const floatx4*)(vp + 4) * aa;
                a2 += *(const floatx4*)(vp + 8) * aa;
                a3 += *(const floatx4*)(vp + 12) * aa;
            }
        }
        float* vout = Vout + ((size_t)b * NN + n0 + row) * DD + dc;
        __builtin_nontemporal_store(a0, (floatx4*)(vout + 0));
        __builtin_nontemporal_store(a1, (floatx4*)(vout + 4));
        __builtin_nontemporal_store(a2, (floatx4*)(vout + 8));
        __builtin_nontemporal_store(a3, (floatx4*)(vout + 12));
    }
}

// ===========================================================================
// FALLBACK PATH — R7 verbatim (735 us, passed) — used if ws too small
// ===========================================================================
__global__ __launch_bounds__(256) void k_convert(const float* __restrict__ Q,
                                                 const float* __restrict__ K,
                                                 _Float16* __restrict__ stash) {
    size_t idx = ((size_t)blockIdx.x * 256 + threadIdx.x) * 4;
    if (idx < (size_t)EE) {
        float4 v = *(const float4*)(Q + idx);
        f16x4 h, l;
        h.x = (_Float16)v.x; h.y = (_Float16)v.y; h.z = (_Float16)v.z; h.w = (_Float16)v.w;
        l.x = (_Float16)(v.x - (float)h.x);
        l.y = (_Float16)(v.y - (float)h.y);
        l.z = (_Float16)(v.z - (float)h.z);
        l.w = (_Float16)(v.w - (float)h.w);
        *(f16x4*)(stash + idx) = h;
        *(f16x4*)(stash + (size_t)EE + idx) = l;
    } else {
        size_t off = idx - (size_t)EE;
        float4 v = *(const float4*)(K + off);
        f16x4 h;
        h.x = (_Float16)v.x; h.y = (_Float16)v.y; h.z = (_Float16)v.z; h.w = (_Float16)v.w;
        *(f16x4*)(stash + 2 * (size_t)EE + off) = h;
    }
}

__global__ __launch_bounds__(256) void k_scores_mfma(const _Float16* __restrict__ stash,
                                                     float* __restrict__ out) {
    __shared__ _Float16 Qh[128 * 32];
    __shared__ _Float16 Ql[128 * 32];
    __shared__ _Float16 Kh[128 * 32];

    const _Float16* Qhi = stash;
    const _Float16* Qlo = stash + (size_t)EE;
    const _Float16* Khi = stash + 2 * (size_t)EE;

    const int b  = blockIdx.z;
    const int n0 = blockIdx.y * 128;
    const int s0 = blockIdx.x * 128;
    const int t    = threadIdx.x;
    const int wave = t >> 6;
    const int lane = t & 63;
    const int srow = (wave << 4) + (lane >> 2);
    const int sd   = (lane & 3) << 3;
    const int lds0 = srow * 32 + sd;
    const size_t qg = (size_t)b * NN * DD + (size_t)(n0 + srow) * DD + sd;
    const size_t kg = (size_t)b * SS * DD + (size_t)(s0 + srow) * DD + sd;
    const int wy = wave >> 1, wx = wave & 1;
    const int frag = (lane & 15) * 32 + (lane >> 4) * 8;

    floatx4 acc[4][4] = {};
    for (int d0 = 0; d0 < DD; d0 += 32) {
        __syncthreads();
        async16(Qhi + qg + d0,            &Qh[lds0]);
        async16(Qhi + qg + d0 + 64 * DD,  &Qh[lds0 + 2048]);
        async16(Qlo + qg + d0,            &Ql[lds0]);
        async16(Qlo + qg + d0 + 64 * DD,  &Ql[lds0 + 2048]);
        async16(Khi + kg + d0,            &Kh[lds0]);
        async16(Khi + kg + d0 + 64 * DD,  &Kh[lds0 + 2048]);
        __syncthreads();
        f16x8 qh[4], ql[4], kh[4];
#pragma unroll
        for (int i = 0; i < 4; ++i) {
            qh[i] = *(const f16x8*)&Qh[(wy * 64 + i * 16) * 32 + frag];
            ql[i] = *(const f16x8*)&Ql[(wy * 64 + i * 16) * 32 + frag];
            kh[i] = *(const f16x8*)&Kh[(wx * 64 + i * 16) * 32 + frag];
        }
#pragma unroll
        for (int i = 0; i < 4; ++i)
#pragma unroll
            for (int j = 0; j < 4; ++j) {
                acc[i][j] = __builtin_amdgcn_mfma_f32_16x16x32_f16(qh[i], kh[j], acc[i][j], 0, 0, 0);
                acc[i][j] = __builtin_amdgcn_mfma_f32_16x16x32_f16(ql[i], kh[j], acc[i][j], 0, 0, 0);
            }
    }
    float* ob = out + (size_t)b * NN * SS;
    const int r0 = n0 + wy * 64 + (lane >> 4) * 4;
    const int c0 = s0 + wx * 64 + (lane & 15);
#pragma unroll
    for (int i = 0; i < 4; ++i)
#pragma unroll
        for (int j = 0; j < 4; ++j)
#pragma unroll
            for (int r = 0; r < 4; ++r)
                ob[(size_t)(r0 + i * 16 + r) * SS + c0 + j * 16] = acc[i][j][r];
}

__global__ __launch_bounds__(256) void k_sparsemax_pv(float* __restrict__ G,
                                                      float* __restrict__ A,
                                                      const float* __restrict__ Val,
                                                      float* __restrict__ Vout) {
    const int t = threadIdx.x;
    const int lane = t & 63;
    const size_t rblk = (size_t)(gridDim.x - 1 - blockIdx.x);
    const size_t row = rblk * 4 + (t >> 6);
    const int b = (int)(row >> 11);
    float* z = G + row * SS;
    float* arow = A + row * SS;
    const float* vb = Val + (size_t)b * SS * DD;

    float v[32];
#pragma unroll
    for (int c = 0; c < 8; ++c) {
        float4 zz = *(const float4*)(z + c * 256 + (lane << 2));
        v[c * 4 + 0] = zz.x; v[c * 4 + 1] = zz.y; v[c * 4 + 2] = zz.z; v[c * 4 + 3] = zz.w;
    }
    float m = v[0];
#pragma unroll
    for (int j = 1; j < 32; ++j) m = fmaxf(m, v[j]);
#pragma unroll
    for (int off = 32; off > 0; off >>= 1) m = fmaxf(m, __shfl_xor(m, off, 64));
    float lo = m - 1.0f, hi = m;
    for (int it = 0; it < 10; ++it) {
        float mid = 0.5f * (lo + hi);
        float p = 0.f;
#pragma unroll
        for (int j = 0; j < 32; ++j) p += fmaxf(v[j] - mid, 0.f);
#pragma unroll
        for (int off = 32; off > 0; off >>= 1) p += __shfl_xor(p, off, 64);
        if (p >= 1.0f) lo = mid; else hi = mid;
    }
    float tau = lo;
#pragma unroll
    for (int it = 0; it < 4; ++it) {
        float cnt = 0.f, s = 0.f;
#pragma unroll
        for (int j = 0; j < 32; ++j) {
            if (v[j] > tau) { cnt += 1.0f; s += v[j]; }
        }
#pragma unroll
        for (int off = 32; off > 0; off >>= 1) {
            cnt += __shfl_xor(cnt, off, 64);
            s   += __shfl_xor(s, off, 64);
        }
        tau = (s - 1.0f) / cnt;
    }
    float g[32];
#pragma unroll
    for (int c = 0; c < 8; ++c) {
#pragma unroll
        for (int q = 0; q < 4; ++q) g[c * 4 + q] = fmaxf(v[c * 4 + q] - tau, 0.f);
        nt_store4(z + c * 256 + (lane << 2),    g[c * 4], g[c * 4 + 1], g[c * 4 + 2], g[c * 4 + 3]);
        nt_store4(arow + c * 256 + (lane << 2), g[c * 4], g[c * 4 + 1], g[c * 4 + 2], g[c * 4 + 3]);
    }
    float4 acc = make_float4(0.f, 0.f, 0.f, 0.f);
#pragma unroll
    for (int c = 0; c < 8; ++c) {
#pragma unroll
        for (int q = 0; q < 4; ++q) {
            float a = g[c * 4 + q];
            unsigned long long mask = __ballot(a != 0.0f);
            while (mask) {
                int src = __builtin_ctzll(mask);
                mask &= mask - 1;
                float aa = __shfl(a, src, 64);
                int s = c * 256 + src * 4 + q;
                float4 vv = *(const float4*)(vb + (size_t)s * DD + lane * 4);
                acc.x += aa * vv.x;
                acc.y += aa * vv.y;
                acc.z += aa * vv.z;
                acc.w += aa * vv.w;
            }
        }
    }
    nt_store4(Vout + row * DD + lane * 4, acc.x, acc.y, acc.z, acc.w);
}

extern "C" void kernel_launch(void* const* d_in, const int* in_sizes, int n_in,
                              void* d_out, int out_size, void* d_ws, size_t ws_size,
                              hipStream_t stream) {
    const float* Q = (const float*)d_in[0];
    const float* K = (const float*)d_in[1];
    const float* V = (const float*)d_in[2];

    float* out  = (float*)d_out;
    float* Vout = out;                                   // [B,N,D]
    float* Aout = out + (size_t)BB * NN * DD;            // [B,N,S]
    float* Gout = Aout + (size_t)BB * NN * SS;           // [B,N,S]

    if (ws_size >= (size_t)EE * sizeof(_Float16)) {
        // MEGA PATH: Kh stash in workspace; one fused kernel for everything else.
        _Float16* kh = (_Float16*)d_ws;
        hipLaunchKernelGGL(k_convert_k, dim3(EE / 4 / 256), dim3(256), 0, stream, K, kh);
        hipLaunchKernelGGL(k_mega, dim3(BB * (NN / 16)), dim3(256), 0, stream,
                           Q, kh, V, Gout, Aout, Vout);
    } else {
        // FALLBACK: proven R7 3-kernel pipeline (stash in Aout region).
        _Float16* stash = (_Float16*)Aout;
        hipLaunchKernelGGL(k_convert, dim3((2 * EE / 4) / 256), dim3(256), 0, stream, Q, K, stash);
        dim3 g1(SS / 128, NN / 128, BB);
        hipLaunchKernelGGL(k_scores_mfma, g1, dim3(256), 0, stream, stash, Gout);
        hipLaunchKernelGGL(k_sparsemax_pv, dim3((BB * NN) / 4), dim3(256), 0, stream,
                           Gout, Aout, V, Vout);
    }
}

// Round 10
// 807.420 us; speedup vs baseline: 1.3341x; 1.2310x over previous
//
#include <hip/hip_runtime.h>
#include <hip/hip_bf16.h>

// Problem constants (B=16, N=S=2048, D=256, fp32 in/out).
#define BB 16
#define NN 2048
#define SS 2048
#define DD 256
#define EE (BB * NN * DD)  // 8388608 elements per tensor
#define QP 264             // padded LDS pitch (f16) for Q strip rows
#define LCAP 32            // list capacity per row per wave

typedef _Float16 f16x8 __attribute__((ext_vector_type(8)));
typedef _Float16 f16x4 __attribute__((ext_vector_type(4)));
typedef float floatx4 __attribute__((ext_vector_type(4)));

__device__ __forceinline__ void async16(const _Float16* g, _Float16* l) {
    __builtin_amdgcn_global_load_lds((__attribute__((address_space(1))) void*)g,
                                     (__attribute__((address_space(3))) void*)l, 16, 0, 0);
}

__device__ __forceinline__ void nt_store4(float* p, float x, float y, float z, float w) {
    floatx4 v = {x, y, z, w};
    __builtin_nontemporal_store(v, (floatx4*)p);
}

// s_waitcnt imm encoding: [3:0]=vmcnt lo, [6:4]=expcnt, [11:8]=lgkmcnt, [15:14]=vmcnt hi
#define FENCE() __builtin_amdgcn_sched_barrier(0)
#define WAIT_VM8() do { FENCE(); __builtin_amdgcn_s_waitcnt(0x0F78); FENCE(); } while (0)
#define WAIT_VM0() do { FENCE(); __builtin_amdgcn_s_waitcnt(0x0F70); FENCE(); } while (0)

// ===========================================================================
// MEGA PATH (requires ws_size >= EE fp16 bytes for the Kh stash)
// ===========================================================================

__global__ __launch_bounds__(256) void k_convert_k(const float* __restrict__ K,
                                                   _Float16* __restrict__ kh) {
    size_t idx = ((size_t)blockIdx.x * 256 + threadIdx.x) * 4;  // over EE
    float4 v = *(const float4*)(K + idx);
    f16x4 h;
    h.x = (_Float16)v.x; h.y = (_Float16)v.y; h.z = (_Float16)v.z; h.w = (_Float16)v.w;
    *(f16x4*)(kh + idx) = h;
}

// One block = 16 query rows x full S. Operand-swapped MFMA: D = K_frag * Q_frag
// so each lane holds 4 CONSECUTIVE COLUMNS of ONE row (row = lane&15) ->
// float4 output stores and scalar per-row reductions.
__global__ __launch_bounds__(256, 2) void k_mega(const float* __restrict__ Qin,
                                                 const _Float16* __restrict__ Kh,
                                                 const float* __restrict__ Val,
                                                 float* __restrict__ G,
                                                 float* __restrict__ A,
                                                 float* __restrict__ Vout) {
    // union region (64 KB): Q hi/lo (phase 0-0.5) -> K dbuf (phase 1) -> lists (3-4)
    __shared__ __align__(16) float fsmem[16384 + 256];
    _Float16* Qh_lds = (_Float16*)fsmem;           // [16][QP]
    _Float16* Ql_lds = (_Float16*)fsmem + 16 * QP;
    _Float16* KB     = (_Float16*)fsmem;           // 4 waves x 2 bufs x 4096 f16
    int*   cols_l = (int*)fsmem;                   // [16][4][LCAP] 8 KB
    float* vals_l = fsmem + 2048;                  // [16][4][LCAP] 8 KB
    float* Mred = fsmem + 16384;                   // [64]
    float* S0   = fsmem + 16448;                   // [64]
    float* S1   = fsmem + 16512;                   // [64]
    int*   cnts = (int*)(fsmem + 16576);           // [16][4]

    const int blk  = blockIdx.x;
    const int b    = blk >> 7;
    const int n0   = (blk & 127) << 4;
    const int t    = threadIdx.x;
    const int wave = t >> 6;
    const int lane = t & 63;
    const int grp  = lane >> 4;           // 0..3 (k-quad / col-quad)
    const int sl   = lane & 15;           // row index within strip
    const int wo   = wave * 8192;         // per-wave K dbuf base (f16 elems)

    // ---- phase 0: Q strip -> LDS fp16 hi/lo (padded)
    {
        const int row = t >> 4;
        const int dc  = (t & 15) << 4;
        const float* qs = Qin + ((size_t)b * NN + n0 + row) * DD + dc;
#pragma unroll
        for (int j = 0; j < 4; ++j) {
            float4 v = *(const float4*)(qs + j * 4);
            f16x4 h, l;
            h.x = (_Float16)v.x; h.y = (_Float16)v.y; h.z = (_Float16)v.z; h.w = (_Float16)v.w;
            l.x = (_Float16)(v.x - (float)h.x);
            l.y = (_Float16)(v.y - (float)h.y);
            l.z = (_Float16)(v.z - (float)h.z);
            l.w = (_Float16)(v.w - (float)h.w);
            *(f16x4*)&Qh_lds[row * QP + dc + j * 4] = h;
            *(f16x4*)&Ql_lds[row * QP + dc + j * 4] = l;
        }
    }
    __syncthreads();

    // ---- phase 0.5: hoist Q fragments to registers (row sl, k-quad grp)
    f16x8 qh[8], ql[8];
    {
        const int fq = sl * QP + grp * 8;
#pragma unroll
        for (int d0 = 0; d0 < 8; ++d0) {
            qh[d0] = *(const f16x8*)&Qh_lds[fq + d0 * 32];
            ql[d0] = *(const f16x8*)&Ql_lds[fq + d0 * 32];
        }
    }
    __syncthreads();  // all q reads done -> K dbuf may overlay Q region

    // ---- phase 1: scores, barrier-free per-wave pipelined K staging.
    // wave owns cols [wave*512, wave*512+512) = 32 tiles of 16 cols.
    floatx4 acc[32] = {};
    const _Float16* kwb = Kh + (((size_t)b * SS) + wave * 512) * DD;

    // stage tile i into buf: 16 rows x 256 f16, XOR-swizzled chunks
    auto stage = [&](int i, int bufsel) {
        const _Float16* kgb = kwb + (size_t)i * 16 * DD;
        _Float16* lb = KB + wo + bufsel * 4096;
#pragma unroll
        for (int j = 0; j < 8; ++j) {
            int u = j * 64 + lane;
            int r = u >> 5;
            int cl = (u & 31) ^ (r & 7);
            async16(kgb + (size_t)r * DD + cl * 8, lb + u * 8);
        }
    };

    stage(0, 0);
    stage(1, 1);
#pragma unroll
    for (int i = 0; i < 32; ++i) {
        if (i == 31) { WAIT_VM0(); } else { WAIT_VM8(); }
        const _Float16* lb = KB + wo + (i & 1) * 4096;
        floatx4 a = acc[i];
#pragma unroll
        for (int d0 = 0; d0 < 8; ++d0) {
            f16x8 kf = *(const f16x8*)&lb[sl * 256 + ((d0 * 4 + grp) ^ (sl & 7)) * 8];
            a = __builtin_amdgcn_mfma_f32_16x16x32_f16(kf, qh[d0], a, 0, 0, 0);
            a = __builtin_amdgcn_mfma_f32_16x16x32_f16(kf, ql[d0], a, 0, 0, 0);
        }
        acc[i] = a;
        FENCE();                       // keep next stage below the ds_reads above
        if (i < 30) stage(i + 2, i & 1);
    }
    // lane now holds row sl, cols wave*512 + i*16 + grp*4 + rr (rr = reg 0..3)

    // ---- phase 2: per-row tau (row = sl; partners are lanes sl+16k)
    float lo, hi;
    {
        float mx = acc[0][0];
#pragma unroll
        for (int i = 0; i < 32; ++i)
#pragma unroll
            for (int rr = 0; rr < 4; ++rr) mx = fmaxf(mx, acc[i][rr]);
        mx = fmaxf(mx, __shfl_xor(mx, 16, 64));
        mx = fmaxf(mx, __shfl_xor(mx, 32, 64));
        if (lane < 16) Mred[wave * 16 + sl] = mx;
        __syncthreads();
        float m = fmaxf(fmaxf(Mred[sl], Mred[16 + sl]), fmaxf(Mred[32 + sl], Mred[48 + sl]));
        lo = m - 1.0f; hi = m;
    }
    for (int it = 0; it < 10; ++it) {
        float* Sw = (it & 1) ? S1 : S0;
        float mid = 0.5f * (lo + hi);
        float p = 0.f;
#pragma unroll
        for (int i = 0; i < 32; ++i)
#pragma unroll
            for (int rr = 0; rr < 4; ++rr) p += fmaxf(acc[i][rr] - mid, 0.f);
        p += __shfl_xor(p, 16, 64);
        p += __shfl_xor(p, 32, 64);
        __syncthreads();
        if (lane < 16) Sw[wave * 16 + sl] = p;
        __syncthreads();
        float P = Sw[sl] + Sw[16 + sl] + Sw[32 + sl] + Sw[48 + sl];
        if (P >= 1.0f) lo = mid; else hi = mid;
    }
    float tau = lo;
    for (int it = 0; it < 4; ++it) {
        float sm = 0.f, ct = 0.f;
#pragma unroll
        for (int i = 0; i < 32; ++i)
#pragma unroll
            for (int rr = 0; rr < 4; ++rr) {
                float z = acc[i][rr];
                if (z > tau) { sm += z; ct += 1.0f; }
            }
        sm += __shfl_xor(sm, 16, 64); sm += __shfl_xor(sm, 32, 64);
        ct += __shfl_xor(ct, 16, 64); ct += __shfl_xor(ct, 32, 64);
        __syncthreads();
        if (lane < 16) { S0[wave * 16 + sl] = sm; S1[wave * 16 + sl] = ct; }
        __syncthreads();
        float S = S0[sl] + S0[16 + sl] + S0[32 + sl] + S0[48 + sl];
        float C = S1[sl] + S1[16 + sl] + S1[32 + sl] + S1[48 + sl];
        tau = (S - 1.0f) / C;
    }

    // ---- phase 3: gates -> float4 nt stores to G,A + list append (lists overlay K)
    int cnt = 0;
    const unsigned long long rowmask = 0x0001000100010001ULL << sl;
    const unsigned long long below  = (1ULL << lane) - 1;
    const size_t rowS = ((size_t)b * NN + n0 + sl) * SS + wave * 512;
#pragma unroll
    for (int i = 0; i < 32; ++i) {
        floatx4 g4;
#pragma unroll
        for (int rr = 0; rr < 4; ++rr) g4[rr] = fmaxf(acc[i][rr] - tau, 0.f);
        __builtin_nontemporal_store(g4, (floatx4*)(G + rowS + i * 16 + grp * 4));
        __builtin_nontemporal_store(g4, (floatx4*)(A + rowS + i * 16 + grp * 4));
#pragma unroll
        for (int rr = 0; rr < 4; ++rr) {
            float gg = g4[rr];
            unsigned long long bm = __ballot(gg > 0.f);
            if (gg > 0.f) {
                int idx = cnt + __popcll(bm & rowmask & below);
                if (idx < LCAP) {
                    cols_l[(sl * 4 + wave) * LCAP + idx] = wave * 512 + i * 16 + grp * 4 + rr;
                    vals_l[(sl * 4 + wave) * LCAP + idx] = gg;
                }
            }
            cnt += (int)__popcll(bm & rowmask);
        }
    }
    if (lane < 16) {
        int c = cnt; if (c > LCAP) c = LCAP;
        cnts[sl * 4 + wave] = c;
    }
    __syncthreads();

    // ---- phase 4: per-row V gather. 16 threads per row, 16 d-elems each.
    {
        const int row = t >> 4;
        const int dc  = (t & 15) << 4;
        const float* vb = Val + (size_t)b * SS * DD;
        floatx4 a0 = {0.f, 0.f, 0.f, 0.f}, a1 = a0, a2 = a0, a3 = a0;
#pragma unroll
        for (int w = 0; w < 4; ++w) {
            const int c = cnts[row * 4 + w];
            for (int i = 0; i < c; ++i) {
                const int col = cols_l[(row * 4 + w) * LCAP + i];
                const float aa = vals_l[(row * 4 + w) * LCAP + i];
                const float* vp = vb + (size_t)col * DD + dc;
                a0 += *(const floatx4*)(vp + 0) * aa;
                a1 += *(const floatx4*)(vp + 4) * aa;
                a2 += *(const floatx4*)(vp + 8) * aa;
                a3 += *(const floatx4*)(vp + 12) * aa;
            }
        }
        float* vout = Vout + ((size_t)b * NN + n0 + row) * DD + dc;
        __builtin_nontemporal_store(a0, (floatx4*)(vout + 0));
        __builtin_nontemporal_store(a1, (floatx4*)(vout + 4));
        __builtin_nontemporal_store(a2, (floatx4*)(vout + 8));
        __builtin_nontemporal_store(a3, (floatx4*)(vout + 12));
    }
}

// ===========================================================================
// FALLBACK PATH — R7 verbatim (735 us, passed) — used if ws too small
// ===========================================================================
__global__ __launch_bounds__(256) void k_convert(const float* __restrict__ Q,
                                                 const float* __restrict__ K,
                                                 _Float16* __restrict__ stash) {
    size_t idx = ((size_t)blockIdx.x * 256 + threadIdx.x) * 4;
    if (idx < (size_t)EE) {
        float4 v = *(const float4*)(Q + idx);
        f16x4 h, l;
        h.x = (_Float16)v.x; h.y = (_Float16)v.y; h.z = (_Float16)v.z; h.w = (_Float16)v.w;
        l.x = (_Float16)(v.x - (float)h.x);
        l.y = (_Float16)(v.y - (float)h.y);
        l.z = (_Float16)(v.z - (float)h.z);
        l.w = (_Float16)(v.w - (float)h.w);
        *(f16x4*)(stash + idx) = h;
        *(f16x4*)(stash + (size_t)EE + idx) = l;
    } else {
        size_t off = idx - (size_t)EE;
        float4 v = *(const float4*)(K + off);
        f16x4 h;
        h.x = (_Float16)v.x; h.y = (_Float16)v.y; h.z = (_Float16)v.z; h.w = (_Float16)v.w;
        *(f16x4*)(stash + 2 * (size_t)EE + off) = h;
    }
}

__global__ __launch_bounds__(256) void k_scores_mfma(const _Float16* __restrict__ stash,
                                                     float* __restrict__ out) {
    __shared__ _Float16 Qh[128 * 32];
    __shared__ _Float16 Ql[128 * 32];
    __shared__ _Float16 Kh[128 * 32];

    const _Float16* Qhi = stash;
    const _Float16* Qlo = stash + (size_t)EE;
    const _Float16* Khi = stash + 2 * (size_t)EE;

    const int b  = blockIdx.z;
    const int n0 = blockIdx.y * 128;
    const int s0 = blockIdx.x * 128;
    const int t    = threadIdx.x;
    const int wave = t >> 6;
    const int lane = t & 63;
    const int srow = (wave << 4) + (lane >> 2);
    const int sd   = (lane & 3) << 3;
    const int lds0 = srow * 32 + sd;
    const size_t qg = (size_t)b * NN * DD + (size_t)(n0 + srow) * DD + sd;
    const size_t kg = (size_t)b * SS * DD + (size_t)(s0 + srow) * DD + sd;
    const int wy = wave >> 1, wx = wave & 1;
    const int frag = (lane & 15) * 32 + (lane >> 4) * 8;

    floatx4 acc[4][4] = {};
    for (int d0 = 0; d0 < DD; d0 += 32) {
        __syncthreads();
        async16(Qhi + qg + d0,            &Qh[lds0]);
        async16(Qhi + qg + d0 + 64 * DD,  &Qh[lds0 + 2048]);
        async16(Qlo + qg + d0,            &Ql[lds0]);
        async16(Qlo + qg + d0 + 64 * DD,  &Ql[lds0 + 2048]);
        async16(Khi + kg + d0,            &Kh[lds0]);
        async16(Khi + kg + d0 + 64 * DD,  &Kh[lds0 + 2048]);
        __syncthreads();
        f16x8 qh[4], ql[4], kh[4];
#pragma unroll
        for (int i = 0; i < 4; ++i) {
            qh[i] = *(const f16x8*)&Qh[(wy * 64 + i * 16) * 32 + frag];
            ql[i] = *(const f16x8*)&Ql[(wy * 64 + i * 16) * 32 + frag];
            kh[i] = *(const f16x8*)&Kh[(wx * 64 + i * 16) * 32 + frag];
        }
#pragma unroll
        for (int i = 0; i < 4; ++i)
#pragma unroll
            for (int j = 0; j < 4; ++j) {
                acc[i][j] = __builtin_amdgcn_mfma_f32_16x16x32_f16(qh[i], kh[j], acc[i][j], 0, 0, 0);
                acc[i][j] = __builtin_amdgcn_mfma_f32_16x16x32_f16(ql[i], kh[j], acc[i][j], 0, 0, 0);
            }
    }
    float* ob = out + (size_t)b * NN * SS;
    const int r0 = n0 + wy * 64 + (lane >> 4) * 4;
    const int c0 = s0 + wx * 64 + (lane & 15);
#pragma unroll
    for (int i = 0; i < 4; ++i)
#pragma unroll
        for (int j = 0; j < 4; ++j)
#pragma unroll
            for (int r = 0; r < 4; ++r)
                ob[(size_t)(r0 + i * 16 + r) * SS + c0 + j * 16] = acc[i][j][r];
}

__global__ __launch_bounds__(256) void k_sparsemax_pv(float* __restrict__ G,
                                                      float* __restrict__ A,
                                                      const float* __restrict__ Val,
                                                      float* __restrict__ Vout) {
    const int t = threadIdx.x;
    const int lane = t & 63;
    const size_t rblk = (size_t)(gridDim.x - 1 - blockIdx.x);
    const size_t row = rblk * 4 + (t >> 6);
    const int b = (int)(row >> 11);
    float* z = G + row * SS;
    float* arow = A + row * SS;
    const float* vb = Val + (size_t)b * SS * DD;

    float v[32];
#pragma unroll
    for (int c = 0; c < 8; ++c) {
        float4 zz = *(const float4*)(z + c * 256 + (lane << 2));
        v[c * 4 + 0] = zz.x; v[c * 4 + 1] = zz.y; v[c * 4 + 2] = zz.z; v[c * 4 + 3] = zz.w;
    }
    float m = v[0];
#pragma unroll
    for (int j = 1; j < 32; ++j) m = fmaxf(m, v[j]);
#pragma unroll
    for (int off = 32; off > 0; off >>= 1) m = fmaxf(m, __shfl_xor(m, off, 64));
    float lo = m - 1.0f, hi = m;
    for (int it = 0; it < 10; ++it) {
        float mid = 0.5f * (lo + hi);
        float p = 0.f;
#pragma unroll
        for (int j = 0; j < 32; ++j) p += fmaxf(v[j] - mid, 0.f);
#pragma unroll
        for (int off = 32; off > 0; off >>= 1) p += __shfl_xor(p, off, 64);
        if (p >= 1.0f) lo = mid; else hi = mid;
    }
    float tau = lo;
#pragma unroll
    for (int it = 0; it < 4; ++it) {
        float cnt = 0.f, s = 0.f;
#pragma unroll
        for (int j = 0; j < 32; ++j) {
            if (v[j] > tau) { cnt += 1.0f; s += v[j]; }
        }
#pragma unroll
        for (int off = 32; off > 0; off >>= 1) {
            cnt += __shfl_xor(cnt, off, 64);
            s   += __shfl_xor(s, off, 64);
        }
        tau = (s - 1.0f) / cnt;
    }
    float g[32];
#pragma unroll
    for (int c = 0; c < 8; ++c) {
#pragma unroll
        for (int q = 0; q < 4; ++q) g[c * 4 + q] = fmaxf(v[c * 4 + q] - tau, 0.f);
        nt_store4(z + c * 256 + (lane << 2),    g[c * 4], g[c * 4 + 1], g[c * 4 + 2], g[c * 4 + 3]);
        nt_store4(arow + c * 256 + (lane << 2), g[c * 4], g[c * 4 + 1], g[c * 4 + 2], g[c * 4 + 3]);
    }
    float4 acc = make_float4(0.f, 0.f, 0.f, 0.f);
#pragma unroll
    for (int c = 0; c < 8; ++c) {
#pragma unroll
        for (int q = 0; q < 4; ++q) {
            float a = g[c * 4 + q];
            unsigned long long mask = __ballot(a != 0.0f);
            while (mask) {
                int src = __builtin_ctzll(mask);
                mask &= mask - 1;
                float aa = __shfl(a, src, 64);
                int s = c * 256 + src * 4 + q;
                float4 vv = *(const float4*)(vb + (size_t)s * DD + lane * 4);
                acc.x += aa * vv.x;
                acc.y += aa * vv.y;
                acc.z += aa * vv.z;
                acc.w += aa * vv.w;
            }
        }
    }
    nt_store4(Vout + row * DD + lane * 4, acc.x, acc.y, acc.z, acc.w);
}

extern "C" void kernel_launch(void* const* d_in, const int* in_sizes, int n_in,
                              void* d_out, int out_size, void* d_ws, size_t ws_size,
                              hipStream_t stream) {
    const float* Q = (const float*)d_in[0];
    const float* K = (const float*)d_in[1];
    const float* V = (const float*)d_in[2];

    float* out  = (float*)d_out;
    float* Vout = out;                                   // [B,N,D]
    float* Aout = out + (size_t)BB * NN * DD;            // [B,N,S]
    float* Gout = Aout + (size_t)BB * NN * SS;           // [B,N,S]

    if (ws_size >= (size_t)EE * sizeof(_Float16)) {
        // MEGA PATH: Kh stash in workspace; one fused kernel for everything else.
        _Float16* kh = (_Float16*)d_ws;
        hipLaunchKernelGGL(k_convert_k, dim3(EE / 4 / 256), dim3(256), 0, stream, K, kh);
        hipLaunchKernelGGL(k_mega, dim3(BB * (NN / 16)), dim3(256), 0, stream,
                           Q, kh, V, Gout, Aout, Vout);
    } else {
        // FALLBACK: proven R7 3-kernel pipeline (stash in Aout region).
        _Float16* stash = (_Float16*)Aout;
        hipLaunchKernelGGL(k_convert, dim3((2 * EE / 4) / 256), dim3(256), 0, stream, Q, K, stash);
        dim3 g1(SS / 128, NN / 128, BB);
        hipLaunchKernelGGL(k_scores_mfma, g1, dim3(256), 0, stream, stash, Gout);
        hipLaunchKernelGGL(k_sparsemax_pv, dim3((BB * NN) / 4), dim3(256), 0, stream,
                           Gout, Aout, V, Vout);
    }
}